// Round 2
// baseline (220.229 us; speedup 1.0000x reference)
//
#include <hip/hip_runtime.h>
#include <hip/hip_bf16.h>

// Problem constants
//   x: (8,2048,768) f32 -> T=16384 tokens, D=768
//   W1/W2/W3: (768,16), b*: (16), grid: (16,16,16,768) f32, temperature scalar
//   out[t,l] = sum_{ijk} p1[t,i] p2[t,j] p3[t,k] grid[i,j,k,l]
// => GEMM M=16384, K=4096 (k=i*256+j*16+kk), N=768 with A built on the fly.

using short8 = __attribute__((ext_vector_type(8))) short;   // 8 bf16 (4 VGPRs)
using f32x4  = __attribute__((ext_vector_type(4))) float;
typedef unsigned short ushort_t;

typedef const __attribute__((address_space(1))) void* gptr_t;
typedef __attribute__((address_space(3))) void* lptr_t;

#define T_TOK   16384
#define PSTRIDE 52            // padded p row stride (floats): 48 used + 4 pad; 16B-multiple

static __device__ __forceinline__ unsigned short f2bf(float x) {
  union { __hip_bfloat16 h; unsigned short s; } u;
  u.h = __float2bfloat16(x);
  return u.s;
}

// ---------------------------------------------------------------------------
// Kernel 1: grid (4096 x 768 f32) -> gridT (768 x 4096 bf16), tiled transpose
// ---------------------------------------------------------------------------
__global__ __launch_bounds__(256) void k_transpose(const float* __restrict__ g,
                                                   ushort_t* __restrict__ gT) {
  __shared__ ushort_t tile[64][65];
  const int tx = threadIdx.x;
  const int r0 = blockIdx.x * 64;   // ijk base (0..4095)
  const int c0 = blockIdx.y * 64;   // l base   (0..767)
#pragma unroll
  for (int it = 0; it < 4; ++it) {
    const int idx = tx + it * 256;            // 0..1023
    const int r = idx >> 4;
    const int c = (idx & 15) << 2;
    const float4 v = *(const float4*)(g + (size_t)(r0 + r) * 768 + (c0 + c));
    tile[c + 0][r] = f2bf(v.x);
    tile[c + 1][r] = f2bf(v.y);
    tile[c + 2][r] = f2bf(v.z);
    tile[c + 3][r] = f2bf(v.w);
  }
  __syncthreads();
#pragma unroll
  for (int it = 0; it < 4; ++it) {
    const int idx = tx + it * 256;
    const int r = idx >> 4;                   // l-local row of gT tile
    const int c = (idx & 15) << 2;            // ijk-local col
    ushort4 o;
    o.x = tile[r][c + 0]; o.y = tile[r][c + 1];
    o.z = tile[r][c + 2]; o.w = tile[r][c + 3];
    *(ushort4*)(gT + (size_t)(c0 + r) * 4096 + (r0 + c)) = o;
  }
}

// ---------------------------------------------------------------------------
// Kernel 2: p[t][48] = softmax16((x@W + b)/temp) for the three 16-groups.
// Block = 256 thr = 4 waves; 64 tokens/block; wave w owns K-quarter (192 d).
// W accessed with wave-uniform indices -> scalar loads.
// ---------------------------------------------------------------------------
__global__ __launch_bounds__(256) void k_prep(const float* __restrict__ x,
                                              const float* __restrict__ W1, const float* __restrict__ b1,
                                              const float* __restrict__ W2, const float* __restrict__ b2,
                                              const float* __restrict__ W3, const float* __restrict__ b3,
                                              const float* __restrict__ temp,
                                              float* __restrict__ p) {
  __shared__ float partial[3][64][48];        // waves 1..3 park partials here
  const int tid = threadIdx.x;
  const int lane = tid & 63;
  const int wv = __builtin_amdgcn_readfirstlane(tid >> 6);
  const int t = blockIdx.x * 64 + lane;

  float acc[48];
#pragma unroll
  for (int g = 0; g < 48; ++g) acc[g] = 0.f;

  const float* xr = x + (size_t)t * 768 + wv * 192;
  for (int d4 = 0; d4 < 48; ++d4) {
    const float4 xv = *(const float4*)(xr + d4 * 4);
    const int dbase = wv * 192 + d4 * 4;
#pragma unroll
    for (int u = 0; u < 4; ++u) {
      const float xs = (u == 0) ? xv.x : (u == 1) ? xv.y : (u == 2) ? xv.z : xv.w;
      const float* w1r = W1 + (dbase + u) * 16;
      const float* w2r = W2 + (dbase + u) * 16;
      const float* w3r = W3 + (dbase + u) * 16;
#pragma unroll
      for (int gg = 0; gg < 16; ++gg) {
        acc[gg]      = fmaf(xs, w1r[gg], acc[gg]);
        acc[16 + gg] = fmaf(xs, w2r[gg], acc[16 + gg]);
        acc[32 + gg] = fmaf(xs, w3r[gg], acc[32 + gg]);
      }
    }
  }

  if (wv > 0) {
#pragma unroll
    for (int g = 0; g < 48; ++g) partial[wv - 1][lane][g] = acc[g];
  }
  __syncthreads();
  if (wv == 0) {
#pragma unroll
    for (int g = 0; g < 48; ++g)
      acc[g] += partial[0][lane][g] + partial[1][lane][g] + partial[2][lane][g];
    const float invT = 1.0f / temp[0];
    const float* bias0 = b1; const float* bias1 = b2; const float* bias2 = b3;
    float* prow = p + (size_t)t * PSTRIDE;
#pragma unroll
    for (int grp = 0; grp < 3; ++grp) {
      const float* bias = (grp == 0) ? bias0 : (grp == 1) ? bias1 : bias2;
      float z[16];
      float m = -3.0e38f;
#pragma unroll
      for (int q = 0; q < 16; ++q) {
        z[q] = (acc[grp * 16 + q] + bias[q]) * invT;
        m = fmaxf(m, z[q]);
      }
      float s = 0.f;
#pragma unroll
      for (int q = 0; q < 16; ++q) { z[q] = __expf(z[q] - m); s += z[q]; }
      const float rs = 1.0f / s;
#pragma unroll
      for (int q = 0; q < 16; ++q) prow[grp * 16 + q] = z[q] * rs;
    }
  }
}

// ---------------------------------------------------------------------------
// Kernel 3: main GEMM. BM=128 BN=128 BK=64, 4 waves (2x2), wave tile 64x64.
// A fragments built in registers from p_lds; B staged via global_load_lds
// with XOR-swizzled source chunks (swizzle c' = c ^ (row&7) on 16B chunks).
// ---------------------------------------------------------------------------
__global__ __launch_bounds__(256, 2) void k_gemm(const float* __restrict__ p_g,
                                                 const ushort_t* __restrict__ gT,
                                                 float* __restrict__ out) {
  __shared__ float p_lds[128 * PSTRIDE];      // 26,624 B
  __shared__ ushort_t Bt[2][128 * 64];        // 2 x 16,384 B (double-buffered)

  const int tid = threadIdx.x;
  const int lane = tid & 63;
  const int wv = __builtin_amdgcn_readfirstlane(tid >> 6);
  const int wm = wv >> 1, wn = wv & 1;
  const int m0 = blockIdx.x * 128;            // token base
  const int n0 = blockIdx.y * 128;            // latent base

  // stage p rows m0..m0+127 (row stride PSTRIDE, 16B-aligned)
  {
    const float4* src = (const float4*)(p_g + (size_t)m0 * PSTRIDE);
    float4* dst = (float4*)p_lds;
    for (int i = tid; i < 128 * PSTRIDE / 4; i += 256) dst[i] = src[i];
  }

  // B staging: wave wv covers rows wv*32..wv*32+31; lane -> (row, chunk')
  const int srow = wv * 32 + (lane >> 3);     // (srow & 7) == lane>>3
  const int sc = (lane & 7) ^ (srow & 7);     // global chunk for this lane's slot
  auto stage = [&](int buf, int kt) {
    const int k0 = kt * 64;
#pragma unroll
    for (int q = 0; q < 4; ++q) {
      const int r = srow + q * 8;
      const ushort_t* src = gT + (size_t)(n0 + r) * 4096 + k0 + sc * 8;
      ushort_t* ldst = &Bt[buf][(wv * 32 + q * 8) * 64];
      __builtin_amdgcn_global_load_lds((gptr_t)src, (lptr_t)ldst, 16, 0, 0);
    }
  };

  f32x4 acc[4][4];
  const f32x4 zero4 = {0.f, 0.f, 0.f, 0.f};
#pragma unroll
  for (int mi = 0; mi < 4; ++mi)
#pragma unroll
    for (int nf = 0; nf < 4; ++nf) acc[mi][nf] = zero4;

  stage(0, 0);
  __syncthreads();

  const int g = lane >> 4;                    // 0..3 (k-group of the wave)
  const int t_low = lane & 15;
  const int p3off = 32 + 8 * (g & 1);         // p3 slice base within p row
  const int jadd = g >> 1;

  for (int kt = 0; kt < 64; ++kt) {
    const int cur = kt & 1;
    if (kt < 63) stage(cur ^ 1, kt + 1);
#pragma unroll
    for (int ks = 0; ks < 2; ++ks) {
      const int kb = kt * 64 + ks * 32;       // global k base of this MFMA step
      const int i_idx = kb >> 8;              // uniform across lanes
      const int j_idx = ((kb >> 4) + jadd) & 15;

      // A fragments: A[m=lane&15][k=8*(lane>>4)+e] = p1[i]*p2[j]*p3[kk]
      short8 a[4];
#pragma unroll
      for (int mi = 0; mi < 4; ++mi) {
        const float* pr = p_lds + (wm * 64 + mi * 16 + t_low) * PSTRIDE;
        const float p12 = pr[i_idx] * pr[16 + j_idx];
        const f32x4 pa = *(const f32x4*)(pr + p3off);
        const f32x4 pb = *(const f32x4*)(pr + p3off + 4);
#pragma unroll
        for (int e = 0; e < 4; ++e) {
          a[mi][e]     = (short)f2bf(p12 * pa[e]);
          a[mi][4 + e] = (short)f2bf(p12 * pb[e]);
        }
      }

      // B fragments: B[k=8g+e][n=lane&15] from swizzled LDS
      short8 b[4];
      const int cd = ks * 4 + g;              // desired 16B chunk 0..7
#pragma unroll
      for (int nf = 0; nf < 4; ++nf) {
        const int r = wn * 64 + nf * 16 + t_low;
        b[nf] = *(const short8*)&Bt[cur][r * 64 + ((cd ^ (r & 7)) << 3)];
      }

#pragma unroll
      for (int mi = 0; mi < 4; ++mi)
#pragma unroll
        for (int nf = 0; nf < 4; ++nf)
          acc[mi][nf] = __builtin_amdgcn_mfma_f32_16x16x32_bf16(a[mi], b[nf], acc[mi][nf], 0, 0, 0);
    }
    __syncthreads();
  }

  // epilogue: D[m=4*(lane>>4)+r][n=lane&15]
  const int rbase = g << 2;
#pragma unroll
  for (int mi = 0; mi < 4; ++mi) {
#pragma unroll
    for (int rr = 0; rr < 4; ++rr) {
      const int t = m0 + wm * 64 + mi * 16 + rbase + rr;
      float* orow = out + (size_t)t * 768 + (n0 + wn * 64 + t_low);
#pragma unroll
      for (int nf = 0; nf < 4; ++nf) orow[nf << 4] = acc[mi][nf][rr];
    }
  }
}

// ---------------------------------------------------------------------------
extern "C" void kernel_launch(void* const* d_in, const int* in_sizes, int n_in,
                              void* d_out, int out_size, void* d_ws, size_t ws_size,
                              hipStream_t stream) {
  (void)in_sizes; (void)n_in; (void)out_size; (void)ws_size;
  const float* x    = (const float*)d_in[0];
  const float* W1   = (const float*)d_in[1];
  const float* b1   = (const float*)d_in[2];
  const float* W2   = (const float*)d_in[3];
  const float* b2   = (const float*)d_in[4];
  const float* W3   = (const float*)d_in[5];
  const float* b3   = (const float*)d_in[6];
  const float* grid = (const float*)d_in[7];
  const float* temp = (const float*)d_in[8];
  float* out = (float*)d_out;

  // workspace layout: gridT bf16 [768][4096] = 6,291,456 B ; p f32 [16384][52] = 3,407,872 B
  ushort_t* gT = (ushort_t*)d_ws;
  float* p = (float*)((char*)d_ws + 6291456);

  k_transpose<<<dim3(64, 12), 256, 0, stream>>>(grid, gT);
  k_prep<<<dim3(256), 256, 0, stream>>>(x, W1, b1, W2, b2, W3, b3, temp, p);
  k_gemm<<<dim3(128, 6), 256, 0, stream>>>(p, gT, out);
}

// Round 3
// 149.439 us; speedup vs baseline: 1.4737x; 1.4737x over previous
//
#include <hip/hip_runtime.h>
#include <hip/hip_bf16.h>

// out[t,l] = sum_{ijk} p1[t,i] p2[t,j] p3[t,k] grid[i,j,k,l]
// GEMM M=16384, K=4096 (k=i*256+j*16+kk), N=768; A built in registers.

using short8 = __attribute__((ext_vector_type(8))) short;   // 8 bf16 (4 VGPRs)
using f32x4  = __attribute__((ext_vector_type(4))) float;
typedef unsigned short ushort_t;
typedef unsigned int uint_t;

typedef const __attribute__((address_space(1))) void* gptr_t;
typedef __attribute__((address_space(3))) void* lptr_t;

#define PSTRIDE 52            // p row stride (floats): 48 used + 4 pad

static __device__ __forceinline__ unsigned short f2bf(float x) {
  union { __hip_bfloat16 h; unsigned short s; } u;
  u.h = __float2bfloat16(x);
  return u.s;
}

// packed f32x2 -> bf16x2, RNE; src0 -> low half
static __device__ __forceinline__ uint_t cvt_pk_bf16(float lo, float hi) {
  uint_t r;
  asm("v_cvt_pk_bf16_f32 %0, %1, %2" : "=v"(r) : "v"(lo), "v"(hi));
  return r;
}

// ---------------------------------------------------------------------------
// Kernel 1: grid (4096 x 768 f32) -> gridT (768 x 4096 bf16)
// ---------------------------------------------------------------------------
__global__ __launch_bounds__(256) void k_transpose(const float* __restrict__ g,
                                                   ushort_t* __restrict__ gT) {
  __shared__ ushort_t tile[64][65];
  const int tx = threadIdx.x;
  const int r0 = blockIdx.x * 64;   // ijk base
  const int c0 = blockIdx.y * 64;   // l base
#pragma unroll
  for (int it = 0; it < 4; ++it) {
    const int idx = tx + it * 256;
    const int r = idx >> 4;
    const int c = (idx & 15) << 2;
    const float4 v = *(const float4*)(g + (size_t)(r0 + r) * 768 + (c0 + c));
    tile[c + 0][r] = f2bf(v.x);
    tile[c + 1][r] = f2bf(v.y);
    tile[c + 2][r] = f2bf(v.z);
    tile[c + 3][r] = f2bf(v.w);
  }
  __syncthreads();
#pragma unroll
  for (int it = 0; it < 4; ++it) {
    const int idx = tx + it * 256;
    const int r = idx >> 4;
    const int c = (idx & 15) << 2;
    ushort4 o;
    o.x = tile[r][c + 0]; o.y = tile[r][c + 1];
    o.z = tile[r][c + 2]; o.w = tile[r][c + 3];
    *(ushort4*)(gT + (size_t)(c0 + r) * 4096 + (r0 + c)) = o;
  }
}

// ---------------------------------------------------------------------------
// Kernel 2: p[t][48] = softmax16((x@W + b)/temp), three 16-groups.
// 512 thr = 8 waves; wave = K-slice (96 d, wave-uniform -> scalar W loads);
// 64 tokens/block (lane = token). Log-tree LDS reduction, softmax in wave 0.
// ---------------------------------------------------------------------------
__global__ __launch_bounds__(512) void k_prep(const float* __restrict__ x,
                                              const float* __restrict__ W1, const float* __restrict__ b1,
                                              const float* __restrict__ W2, const float* __restrict__ b2,
                                              const float* __restrict__ W3, const float* __restrict__ b3,
                                              const float* __restrict__ temp,
                                              float* __restrict__ p) {
  __shared__ float partial[4][64][PSTRIDE];   // 53,248 B
  const int tid = threadIdx.x;
  const int lane = tid & 63;
  const int wv = __builtin_amdgcn_readfirstlane(tid >> 6);  // 0..7 = K-slice
  const int t = blockIdx.x * 64 + lane;

  float acc[48];
#pragma unroll
  for (int g = 0; g < 48; ++g) acc[g] = 0.f;

  const float* xr = x + (size_t)t * 768 + wv * 96;
  for (int d4 = 0; d4 < 24; ++d4) {
    const float4 xv = *(const float4*)(xr + d4 * 4);
    const int dbase = wv * 96 + d4 * 4;
#pragma unroll
    for (int u = 0; u < 4; ++u) {
      const float xs = (u == 0) ? xv.x : (u == 1) ? xv.y : (u == 2) ? xv.z : xv.w;
      const float* w1r = W1 + (dbase + u) * 16;
      const float* w2r = W2 + (dbase + u) * 16;
      const float* w3r = W3 + (dbase + u) * 16;
#pragma unroll
      for (int gg = 0; gg < 16; ++gg) {
        acc[gg]      = fmaf(xs, w1r[gg], acc[gg]);
        acc[16 + gg] = fmaf(xs, w2r[gg], acc[16 + gg]);
        acc[32 + gg] = fmaf(xs, w3r[gg], acc[32 + gg]);
      }
    }
  }

  // tree reduce 8 -> 4 -> 2 -> 1 (planes reused)
  if (wv >= 4) {
    f32x4* dst = (f32x4*)partial[wv - 4][lane];
#pragma unroll
    for (int q = 0; q < 12; ++q) dst[q] = *(const f32x4*)&acc[q * 4];
  }
  __syncthreads();
  if (wv < 4) {
    const f32x4* src = (const f32x4*)partial[wv][lane];
#pragma unroll
    for (int q = 0; q < 12; ++q) {
      const f32x4 v = src[q];
#pragma unroll
      for (int e = 0; e < 4; ++e) acc[q * 4 + e] += v[e];
    }
  }
  __syncthreads();
  if (wv == 2 || wv == 3) {
    f32x4* dst = (f32x4*)partial[wv - 2][lane];
#pragma unroll
    for (int q = 0; q < 12; ++q) dst[q] = *(const f32x4*)&acc[q * 4];
  }
  __syncthreads();
  if (wv < 2) {
    const f32x4* src = (const f32x4*)partial[wv][lane];
#pragma unroll
    for (int q = 0; q < 12; ++q) {
      const f32x4 v = src[q];
#pragma unroll
      for (int e = 0; e < 4; ++e) acc[q * 4 + e] += v[e];
    }
  }
  __syncthreads();
  if (wv == 1) {
    f32x4* dst = (f32x4*)partial[0][lane];
#pragma unroll
    for (int q = 0; q < 12; ++q) dst[q] = *(const f32x4*)&acc[q * 4];
  }
  __syncthreads();
  if (wv == 0) {
    const f32x4* src = (const f32x4*)partial[0][lane];
#pragma unroll
    for (int q = 0; q < 12; ++q) {
      const f32x4 v = src[q];
#pragma unroll
      for (int e = 0; e < 4; ++e) acc[q * 4 + e] += v[e];
    }
    const float invT = 1.0f / temp[0];
    float* prow = p + (size_t)t * PSTRIDE;
#pragma unroll
    for (int grp = 0; grp < 3; ++grp) {
      const float* bias = (grp == 0) ? b1 : (grp == 1) ? b2 : b3;
      float z[16];
      float m = -3.0e38f;
#pragma unroll
      for (int q = 0; q < 16; ++q) {
        z[q] = (acc[grp * 16 + q] + bias[q]) * invT;
        m = fmaxf(m, z[q]);
      }
      float s = 0.f;
#pragma unroll
      for (int q = 0; q < 16; ++q) { z[q] = __expf(z[q] - m); s += z[q]; }
      const float rs = 1.0f / s;
#pragma unroll
      for (int q = 0; q < 16; ++q) prow[grp * 16 + q] = z[q] * rs;
    }
  }
}

// ---------------------------------------------------------------------------
// Kernel 3: GEMM. BM=128 BN=192 BK=64, 4 waves (2x2), wave tile 64x96 (nf=6).
// A built in registers (cvt_pk_bf16); p3 slices hoisted out of K-loop.
// B staged via global_load_lds, XOR-swizzled 16B chunks (both-sides rule).
// Grid = 128 x 4 = 512 blocks = exactly 2/CU.
// ---------------------------------------------------------------------------
__global__ __launch_bounds__(256, 2) void k_gemm(const float* __restrict__ p_g,
                                                 const ushort_t* __restrict__ gT,
                                                 float* __restrict__ out) {
  __shared__ float p_lds[128 * PSTRIDE];      // 26,624 B
  __shared__ ushort_t Bt[2][192 * 64];        // 2 x 24,576 B

  const int tid = threadIdx.x;
  const int lane = tid & 63;
  const int wv = __builtin_amdgcn_readfirstlane(tid >> 6);
  const int wm = wv >> 1, wn = wv & 1;
  const int m0 = blockIdx.x * 128;
  const int n0 = blockIdx.y * 192;

  // stage p rows m0..m0+127
  {
    const float4* src = (const float4*)(p_g + (size_t)m0 * PSTRIDE);
    float4* dst = (float4*)p_lds;
    for (int i = tid; i < 128 * PSTRIDE / 4; i += 256) dst[i] = src[i];
  }

  // B staging: wave covers 48 rows (6 issues x 8 rows); lane -> (row, chunk')
  const int srow = wv * 48 + (lane >> 3);     // (srow & 7) == lane>>3
  const int sc = (lane & 7) ^ (lane >> 3);    // global chunk for this lane's slot
  auto stage = [&](int buf, int kt) {
    const int k0 = kt * 64;
#pragma unroll
    for (int q = 0; q < 6; ++q) {
      const int r = srow + q * 8;
      const ushort_t* src = gT + (size_t)(n0 + r) * 4096 + k0 + sc * 8;
      ushort_t* ldst = &Bt[buf][(wv * 48 + q * 8) * 64];
      __builtin_amdgcn_global_load_lds((gptr_t)src, (lptr_t)ldst, 16, 0, 0);
    }
  };

  f32x4 acc[4][6];
  const f32x4 zero4 = {0.f, 0.f, 0.f, 0.f};
#pragma unroll
  for (int mi = 0; mi < 4; ++mi)
#pragma unroll
    for (int nf = 0; nf < 6; ++nf) acc[mi][nf] = zero4;

  stage(0, 0);
  __syncthreads();

  const int g = lane >> 4;                    // k-group 0..3
  const int t_low = lane & 15;
  const int p3off = 32 + 8 * (g & 1);
  const int jadd = g >> 1;

  // hoist p3 fragments (kt-invariant)
  const float* prow[4];
  f32x4 pa[4], pb[4];
#pragma unroll
  for (int mi = 0; mi < 4; ++mi) {
    prow[mi] = p_lds + (wm * 64 + mi * 16 + t_low) * PSTRIDE;
    pa[mi] = *(const f32x4*)(prow[mi] + p3off);
    pb[mi] = *(const f32x4*)(prow[mi] + p3off + 4);
  }

  for (int kt = 0; kt < 64; ++kt) {
    const int cur = kt & 1;
    if (kt < 63) stage(cur ^ 1, kt + 1);
#pragma unroll
    for (int ks = 0; ks < 2; ++ks) {
      const int kb = kt * 64 + ks * 32;
      const int i_idx = kb >> 8;
      const int j_idx = ((kb >> 4) + jadd) & 15;

      short8 a[4];
#pragma unroll
      for (int mi = 0; mi < 4; ++mi) {
        const float p12 = prow[mi][i_idx] * prow[mi][16 + j_idx];
        union { uint_t u[4]; short8 s8; } pk;
        pk.u[0] = cvt_pk_bf16(p12 * pa[mi][0], p12 * pa[mi][1]);
        pk.u[1] = cvt_pk_bf16(p12 * pa[mi][2], p12 * pa[mi][3]);
        pk.u[2] = cvt_pk_bf16(p12 * pb[mi][0], p12 * pb[mi][1]);
        pk.u[3] = cvt_pk_bf16(p12 * pb[mi][2], p12 * pb[mi][3]);
        a[mi] = pk.s8;
      }

      short8 b[6];
      const int cd = ks * 4 + g;
#pragma unroll
      for (int nf = 0; nf < 6; ++nf) {
        const int r = wn * 96 + nf * 16 + t_low;
        b[nf] = *(const short8*)&Bt[cur][r * 64 + ((cd ^ (r & 7)) << 3)];
      }

#pragma unroll
      for (int mi = 0; mi < 4; ++mi)
#pragma unroll
        for (int nf = 0; nf < 6; ++nf)
          acc[mi][nf] = __builtin_amdgcn_mfma_f32_16x16x32_bf16(a[mi], b[nf], acc[mi][nf], 0, 0, 0);
    }
    __syncthreads();
  }

  // epilogue: D[m=4*(lane>>4)+r][n=lane&15]
  const int rbase = g << 2;
#pragma unroll
  for (int mi = 0; mi < 4; ++mi) {
#pragma unroll
    for (int rr = 0; rr < 4; ++rr) {
      const int t = m0 + wm * 64 + mi * 16 + rbase + rr;
      float* orow = out + (size_t)t * 768 + (n0 + wn * 96 + t_low);
#pragma unroll
      for (int nf = 0; nf < 6; ++nf) orow[nf << 4] = acc[mi][nf][rr];
    }
  }
}

// ---------------------------------------------------------------------------
extern "C" void kernel_launch(void* const* d_in, const int* in_sizes, int n_in,
                              void* d_out, int out_size, void* d_ws, size_t ws_size,
                              hipStream_t stream) {
  (void)in_sizes; (void)n_in; (void)out_size; (void)ws_size;
  const float* x    = (const float*)d_in[0];
  const float* W1   = (const float*)d_in[1];
  const float* b1   = (const float*)d_in[2];
  const float* W2   = (const float*)d_in[3];
  const float* b2   = (const float*)d_in[4];
  const float* W3   = (const float*)d_in[5];
  const float* b3   = (const float*)d_in[6];
  const float* grid = (const float*)d_in[7];
  const float* temp = (const float*)d_in[8];
  float* out = (float*)d_out;

  // ws: gridT bf16 [768][4096] = 6,291,456 B ; p f32 [16384][52] = 3,407,872 B
  ushort_t* gT = (ushort_t*)d_ws;
  float* p = (float*)((char*)d_ws + 6291456);

  k_transpose<<<dim3(64, 12), 256, 0, stream>>>(grid, gT);
  k_prep<<<dim3(256), 512, 0, stream>>>(x, W1, b1, W2, b2, W3, b3, temp, p);
  k_gemm<<<dim3(128, 4), 256, 0, stream>>>(p, gT, out);
}

// Round 4
// 147.857 us; speedup vs baseline: 1.4895x; 1.0107x over previous
//
#include <hip/hip_runtime.h>
#include <hip/hip_bf16.h>

// out[t,l] = sum_{ijk} p1[t,i] p2[t,j] p3[t,k] grid[i,j,k,l]
// GEMM M=16384, K=4096 (k=i*256+j*16+kk), N=768; A built in registers.
// v4: 32x32x16 MFMA, raw-barrier 2-phase pipeline, p fully in regs/p1T-LDS,
//     coalesced chunked k_prep (fixes 4x x-overfetch).

using short8 = __attribute__((ext_vector_type(8))) short;   // 8 bf16
using f32x4  = __attribute__((ext_vector_type(4))) float;
using f32x16 = __attribute__((ext_vector_type(16))) float;
typedef unsigned short ushort_t;
typedef unsigned int uint_t;

typedef const __attribute__((address_space(1))) void* gptr_t;
typedef __attribute__((address_space(3))) void* lptr_t;

#define PSTRIDE 52            // p row stride (floats)

static __device__ __forceinline__ unsigned short f2bf(float x) {
  union { __hip_bfloat16 h; unsigned short s; } u;
  u.h = __float2bfloat16(x);
  return u.s;
}

// packed f32x2 -> bf16x2 (RNE); src0 -> low half
static __device__ __forceinline__ uint_t cvt_pk_bf16(float lo, float hi) {
  uint_t r;
  asm("v_cvt_pk_bf16_f32 %0, %1, %2" : "=v"(r) : "v"(lo), "v"(hi));
  return r;
}

// ---------------------------------------------------------------------------
// Kernel 1: grid (4096 x 768 f32) -> gridT (768 x 4096 bf16)
// ---------------------------------------------------------------------------
__global__ __launch_bounds__(256) void k_transpose(const float* __restrict__ g,
                                                   ushort_t* __restrict__ gT) {
  __shared__ ushort_t tile[64][65];
  const int tx = threadIdx.x;
  const int r0 = blockIdx.x * 64;   // ijk base
  const int c0 = blockIdx.y * 64;   // l base
#pragma unroll
  for (int it = 0; it < 4; ++it) {
    const int idx = tx + it * 256;
    const int r = idx >> 4;
    const int c = (idx & 15) << 2;
    const float4 v = *(const float4*)(g + (size_t)(r0 + r) * 768 + (c0 + c));
    tile[c + 0][r] = f2bf(v.x);
    tile[c + 1][r] = f2bf(v.y);
    tile[c + 2][r] = f2bf(v.z);
    tile[c + 3][r] = f2bf(v.w);
  }
  __syncthreads();
#pragma unroll
  for (int it = 0; it < 4; ++it) {
    const int idx = tx + it * 256;
    const int r = idx >> 4;
    const int c = (idx & 15) << 2;
    ushort4 o;
    o.x = tile[r][c + 0]; o.y = tile[r][c + 1];
    o.z = tile[r][c + 2]; o.w = tile[r][c + 3];
    *(ushort4*)(gT + (size_t)(c0 + r) * 4096 + (r0 + c)) = o;
  }
}

// ---------------------------------------------------------------------------
// Kernel 2: p[t][48] = softmax16((x@W + b)/temp), three 16-groups.
// 512 thr = 8 waves; 64 tokens/block. x staged in LDS chunks (COALESCED
// global reads, double-buffered); wave wv accumulates d-slice wv*12..+12
// of each 96-d chunk. Tree reduce 8->4->2->1, softmax on wave 0.
// ---------------------------------------------------------------------------
__global__ __launch_bounds__(512) void k_prep(const float* __restrict__ x,
                                              const float* __restrict__ W1, const float* __restrict__ b1,
                                              const float* __restrict__ W2, const float* __restrict__ b2,
                                              const float* __restrict__ W3, const float* __restrict__ b3,
                                              const float* __restrict__ temp,
                                              float* __restrict__ p) {
  __shared__ union SmT {
    float x2[2][64][100];                   // 51,200 B  (pad 100 keeps 16B align)
    float partial[4][64][PSTRIDE];          // 53,248 B
  } sm;
  const int tid = threadIdx.x;
  const int lane = tid & 63;
  const int wv = __builtin_amdgcn_readfirstlane(tid >> 6);  // 0..7 = d-slice
  const int t0 = blockIdx.x * 64;

  float acc[48];
#pragma unroll
  for (int g = 0; g < 48; ++g) acc[g] = 0.f;

  const float* xbase = x + (size_t)t0 * 768;
  auto load_chunk = [&](int c, int b) {
#pragma unroll
    for (int it = 0; it < 3; ++it) {
      const int q = tid + it * 512;         // 0..1535
      const int r = q / 24;                 // token row 0..63
      const int c4 = q % 24;                // f32x4 slot in 96
      const float4 v = *(const float4*)(xbase + (size_t)r * 768 + c * 96 + c4 * 4);
      *(float4*)&sm.x2[b][r][c4 * 4] = v;
    }
  };

  load_chunk(0, 0);
  __syncthreads();
  for (int c = 0; c < 8; ++c) {
    const int cur = c & 1;
    if (c < 7) load_chunk(c + 1, cur ^ 1);
    float xv[12];
#pragma unroll
    for (int rr = 0; rr < 3; ++rr) {
      const f32x4 v = *(const f32x4*)&sm.x2[cur][lane][wv * 12 + rr * 4];
      xv[rr * 4 + 0] = v[0]; xv[rr * 4 + 1] = v[1];
      xv[rr * 4 + 2] = v[2]; xv[rr * 4 + 3] = v[3];
    }
#pragma unroll
    for (int dd = 0; dd < 12; ++dd) {
      const int d = c * 96 + wv * 12 + dd;
      const float xs = xv[dd];
      const float* w1r = W1 + d * 16;
      const float* w2r = W2 + d * 16;
      const float* w3r = W3 + d * 16;
#pragma unroll
      for (int gg = 0; gg < 16; ++gg) {
        acc[gg]      = fmaf(xs, w1r[gg], acc[gg]);
        acc[16 + gg] = fmaf(xs, w2r[gg], acc[16 + gg]);
        acc[32 + gg] = fmaf(xs, w3r[gg], acc[32 + gg]);
      }
    }
    __syncthreads();
  }

  // tree reduce 8 -> 4 -> 2 -> 1
  if (wv >= 4) {
    f32x4* dst = (f32x4*)sm.partial[wv - 4][lane];
#pragma unroll
    for (int q = 0; q < 12; ++q) dst[q] = *(const f32x4*)&acc[q * 4];
  }
  __syncthreads();
  if (wv < 4) {
    const f32x4* src = (const f32x4*)sm.partial[wv][lane];
#pragma unroll
    for (int q = 0; q < 12; ++q) {
      const f32x4 v = src[q];
#pragma unroll
      for (int e = 0; e < 4; ++e) acc[q * 4 + e] += v[e];
    }
  }
  __syncthreads();
  if (wv == 2 || wv == 3) {
    f32x4* dst = (f32x4*)sm.partial[wv - 2][lane];
#pragma unroll
    for (int q = 0; q < 12; ++q) dst[q] = *(const f32x4*)&acc[q * 4];
  }
  __syncthreads();
  if (wv < 2) {
    const f32x4* src = (const f32x4*)sm.partial[wv][lane];
#pragma unroll
    for (int q = 0; q < 12; ++q) {
      const f32x4 v = src[q];
#pragma unroll
      for (int e = 0; e < 4; ++e) acc[q * 4 + e] += v[e];
    }
  }
  __syncthreads();
  if (wv == 1) {
    f32x4* dst = (f32x4*)sm.partial[0][lane];
#pragma unroll
    for (int q = 0; q < 12; ++q) dst[q] = *(const f32x4*)&acc[q * 4];
  }
  __syncthreads();
  if (wv == 0) {
    const f32x4* src = (const f32x4*)sm.partial[0][lane];
#pragma unroll
    for (int q = 0; q < 12; ++q) {
      const f32x4 v = src[q];
#pragma unroll
      for (int e = 0; e < 4; ++e) acc[q * 4 + e] += v[e];
    }
    const float invT = 1.0f / temp[0];
    float* prow = p + (size_t)(t0 + lane) * PSTRIDE;
#pragma unroll
    for (int grp = 0; grp < 3; ++grp) {
      const float* bias = (grp == 0) ? b1 : (grp == 1) ? b2 : b3;
      float z[16];
      float m = -3.0e38f;
#pragma unroll
      for (int q = 0; q < 16; ++q) {
        z[q] = (acc[grp * 16 + q] + bias[q]) * invT;
        m = fmaxf(m, z[q]);
      }
      float s = 0.f;
#pragma unroll
      for (int q = 0; q < 16; ++q) { z[q] = __expf(z[q] - m); s += z[q]; }
      const float rs = 1.0f / s;
#pragma unroll
      for (int q = 0; q < 16; ++q) prow[grp * 16 + q] = z[q] * rs;
    }
  }
}

// ---------------------------------------------------------------------------
// Kernel 3: GEMM. BM=128 BN=192 BK=64; 4 waves 2x2, wave tile 64x96 using
// v_mfma_f32_32x32x16_bf16 (2 m-reps x 3 n-frags). p2/p3 per-lane in regs
// (static indexing), p1 via LDS-transposed p1T (wave-uniform i). Raw-barrier
// 2-phase: stage(kt+1) issued right after barrier, vmcnt drains only before
// next barrier -> loads in flight under full compute phase. XCD swizzle.
// ---------------------------------------------------------------------------
__global__ __launch_bounds__(256, 2) void k_gemm(const float* __restrict__ p_g,
                                                 const ushort_t* __restrict__ gT,
                                                 float* __restrict__ out) {
  __shared__ ushort_t Bt[2][192 * 64];        // 49,152 B
  __shared__ float p1T[16 * 128];             //  8,192 B

  const int tid = threadIdx.x;
  const int lane = tid & 63;
  const int wv = __builtin_amdgcn_readfirstlane(tid >> 6);
  const int wm = wv >> 1, wn = wv & 1;
  const int g = lane >> 5;                    // k-half 0/1
  const int l31 = lane & 31;

  // XCD-aware swizzle over 512 blocks (512 % 8 == 0 -> bijective)
  const int f = blockIdx.y * 128 + blockIdx.x;
  const int w = (f & 7) * 64 + (f >> 3);
  const int m0 = (w & 127) * 128;
  const int n0 = (w >> 7) * 192;

  // p1T[i][row] cooperative build
  if (tid < 128) {
    const float* pr = p_g + (size_t)(m0 + tid) * PSTRIDE;
#pragma unroll
    for (int qq = 0; qq < 4; ++qq) {
      const f32x4 v = *(const f32x4*)(pr + qq * 4);
#pragma unroll
      for (int e = 0; e < 4; ++e) p1T[(qq * 4 + e) * 128 + tid] = v[e];
    }
  }

  // per-lane p2 (16) and p3 (its k-half, 8) for both m-rep rows
  const int rowA0 = m0 + wm * 64 + l31;
  float p2r[2][16], p3r[2][8];
#pragma unroll
  for (int mr = 0; mr < 2; ++mr) {
    const float* pr = p_g + (size_t)(rowA0 + mr * 32) * PSTRIDE;
#pragma unroll
    for (int qq = 0; qq < 4; ++qq) {
      const f32x4 v = *(const f32x4*)(pr + 16 + qq * 4);
      p2r[mr][qq * 4 + 0] = v[0]; p2r[mr][qq * 4 + 1] = v[1];
      p2r[mr][qq * 4 + 2] = v[2]; p2r[mr][qq * 4 + 3] = v[3];
    }
#pragma unroll
    for (int qq = 0; qq < 2; ++qq) {
      const f32x4 v = *(const f32x4*)(pr + 32 + 8 * g + qq * 4);
      p3r[mr][qq * 4 + 0] = v[0]; p3r[mr][qq * 4 + 1] = v[1];
      p3r[mr][qq * 4 + 2] = v[2]; p3r[mr][qq * 4 + 3] = v[3];
    }
  }

  // B staging: wave covers 48 rows; lane -> (row = lane>>3, slot = lane&7),
  // source chunk = slot ^ (row&7)  [inverse-swizzled source, linear LDS dest]
  const int srow = wv * 48 + (lane >> 3);
  const int schunk = (lane & 7) ^ (lane >> 3);
  const ushort_t* sbase = gT + (size_t)(n0 + srow) * 4096 + schunk * 8;
  auto stage = [&](int buf, int kt) {
    const ushort_t* src = sbase + kt * 64;
#pragma unroll
    for (int q = 0; q < 6; ++q) {
      __builtin_amdgcn_global_load_lds((gptr_t)(src + (size_t)q * 8 * 4096),
                                       (lptr_t)&Bt[buf][(wv * 48 + q * 8) * 64], 16, 0, 0);
    }
  };

  f32x16 acc[2][3];
#pragma unroll
  for (int mr = 0; mr < 2; ++mr)
#pragma unroll
    for (int nf = 0; nf < 3; ++nf)
#pragma unroll
      for (int e = 0; e < 16; ++e) acc[mr][nf][e] = 0.f;

  stage(0, 0);
  asm volatile("s_waitcnt vmcnt(0) lgkmcnt(0)" ::: "memory");  // stage0 + p1T done
  __builtin_amdgcn_s_barrier();

  const int rowLoc0 = wm * 64 + l31;
  for (int io = 0; io < 16; ++io) {           // i-index (p1), rolled
    float p1p3[2][8];
#pragma unroll
    for (int mr = 0; mr < 2; ++mr) {
      const float p1v = p1T[io * 128 + rowLoc0 + mr * 32];
#pragma unroll
      for (int e = 0; e < 8; ++e) p1p3[mr][e] = p1v * p3r[mr][e];
    }
#pragma unroll
    for (int kq = 0; kq < 4; ++kq) {          // kt = io*4+kq; kt&1 == kq&1
      const int kt = io * 4 + kq;
      if (kq < 3 || io < 15) stage((kq + 1) & 1, kt + 1);
      const ushort_t* bbuf = Bt[kq & 1];
#pragma unroll
      for (int s = 0; s < 4; ++s) {
        const int j = kq * 4 + s;             // static -> p2r static index
        short8 a[2];
#pragma unroll
        for (int mr = 0; mr < 2; ++mr) {
          const float pj = p2r[mr][j];
          union { uint_t u[4]; short8 s8; } pk;
          pk.u[0] = cvt_pk_bf16(pj * p1p3[mr][0], pj * p1p3[mr][1]);
          pk.u[1] = cvt_pk_bf16(pj * p1p3[mr][2], pj * p1p3[mr][3]);
          pk.u[2] = cvt_pk_bf16(pj * p1p3[mr][4], pj * p1p3[mr][5]);
          pk.u[3] = cvt_pk_bf16(pj * p1p3[mr][6], pj * p1p3[mr][7]);
          a[mr] = pk.s8;
        }
        const int cd = 2 * s + g;
        short8 b[3];
#pragma unroll
        for (int nf = 0; nf < 3; ++nf) {
          const int r = wn * 96 + nf * 32 + l31;
          b[nf] = *(const short8*)&bbuf[r * 64 + ((cd ^ (r & 7)) << 3)];
        }
#pragma unroll
        for (int mr = 0; mr < 2; ++mr)
#pragma unroll
          for (int nf = 0; nf < 3; ++nf)
            acc[mr][nf] = __builtin_amdgcn_mfma_f32_32x32x16_bf16(a[mr], b[nf], acc[mr][nf], 0, 0, 0);
      }
      // only the 6 just-issued stage loads are outstanding here
      asm volatile("s_waitcnt vmcnt(0)" ::: "memory");
      __builtin_amdgcn_s_barrier();
    }
  }

  // epilogue: 32x32 C/D layout: col = lane&31, row = (reg&3)+8*(reg>>2)+4*(lane>>5)
#pragma unroll
  for (int mr = 0; mr < 2; ++mr)
#pragma unroll
    for (int nf = 0; nf < 3; ++nf)
#pragma unroll
      for (int reg = 0; reg < 16; ++reg) {
        const int row = (reg & 3) + 8 * (reg >> 2) + 4 * g;
        const int t = m0 + wm * 64 + mr * 32 + row;
        out[(size_t)t * 768 + n0 + wn * 96 + nf * 32 + l31] = acc[mr][nf][reg];
      }
}

// ---------------------------------------------------------------------------
extern "C" void kernel_launch(void* const* d_in, const int* in_sizes, int n_in,
                              void* d_out, int out_size, void* d_ws, size_t ws_size,
                              hipStream_t stream) {
  (void)in_sizes; (void)n_in; (void)out_size; (void)ws_size;
  const float* x    = (const float*)d_in[0];
  const float* W1   = (const float*)d_in[1];
  const float* b1   = (const float*)d_in[2];
  const float* W2   = (const float*)d_in[3];
  const float* b2   = (const float*)d_in[4];
  const float* W3   = (const float*)d_in[5];
  const float* b3   = (const float*)d_in[6];
  const float* grid = (const float*)d_in[7];
  const float* temp = (const float*)d_in[8];
  float* out = (float*)d_out;

  // ws: gridT bf16 [768][4096] = 6,291,456 B ; p f32 [16384][52] = 3,407,872 B
  ushort_t* gT = (ushort_t*)d_ws;
  float* p = (float*)((char*)d_ws + 6291456);

  k_transpose<<<dim3(64, 12), 256, 0, stream>>>(grid, gT);
  k_prep<<<dim3(256), 512, 0, stream>>>(x, W1, b1, W2, b2, W3, b3, temp, p);
  k_gemm<<<dim3(128, 4), 256, 0, stream>>>(p, gT, out);
}

// Round 6
// 131.272 us; speedup vs baseline: 1.6776x; 1.1263x over previous
//
#include <hip/hip_runtime.h>
#include <hip/hip_bf16.h>

// out[t,l] = sum_{ijk} p1[t,i] p2[t,j] p3[t,k] grid[i,j,k,l]
// GEMM M=16384, K=4096 (k=i*256+j*16+kk), N=768; A built in registers.
// v5b: f16 A/B (v_pk_mul_f16 A-build), straight-line kt body with setprio
//      MFMA clusters, fused transpose+prep kernel. (fixes cvt_pkrtz type)

using short8 = __attribute__((ext_vector_type(8))) short;
using f32x4  = __attribute__((ext_vector_type(4))) float;
using f32x16 = __attribute__((ext_vector_type(16))) float;
using half8  = __attribute__((ext_vector_type(8))) _Float16;
using half2v = __attribute__((ext_vector_type(2))) _Float16;
typedef unsigned short ushort_t;
typedef unsigned int uint_t;

typedef const __attribute__((address_space(1))) void* gptr_t;
typedef __attribute__((address_space(3))) void* lptr_t;

#define PSTRIDE 52            // p row stride (floats)

static __device__ __forceinline__ ushort_t f2h_bits(float x) {
  union { _Float16 h; ushort_t u; } c;
  c.h = (_Float16)x;          // RNE
  return c.u;
}

// packed f32x2 -> f16x2 (RTZ), bit-cast to _Float16 vector
static __device__ __forceinline__ half2v cvt_pkrtz2(float a, float b) {
  auto r = __builtin_amdgcn_cvt_pkrtz(a, b);
  union { decltype(r) i; half2v o; } u;
  u.i = r;
  return u.o;
}

// ---------------------------------------------------------------------------
// Fused pre-kernel: blocks 0..767 transpose grid -> gT (f16, [768][4096]);
// blocks 768..1023 compute p[t][48] = softmax16((x@W+b)/temp) (f32).
// ---------------------------------------------------------------------------
__global__ __launch_bounds__(512) void k_pre(const float* __restrict__ g,
                                             ushort_t* __restrict__ gT,
                                             const float* __restrict__ x,
                                             const float* __restrict__ W1, const float* __restrict__ b1,
                                             const float* __restrict__ W2, const float* __restrict__ b2,
                                             const float* __restrict__ W3, const float* __restrict__ b3,
                                             const float* __restrict__ temp,
                                             float* __restrict__ p) {
  __shared__ union SmT {
    ushort_t tile[64][65];                  //  8,320 B (transpose path)
    float x2[2][64][100];                   // 51,200 B (prep path)
    float partial[4][64][PSTRIDE];          // 53,248 B (prep path)
  } sm;
  const int tid = threadIdx.x;
  const int bid = blockIdx.x;

  if (bid < 768) {
    // ---- transpose tile: grid (4096 x 768 f32) -> gT (768 x 4096 f16) ----
    const int r0 = (bid & 63) * 64;         // ijk base
    const int c0 = (bid >> 6) * 64;         // l base
#pragma unroll
    for (int it = 0; it < 2; ++it) {
      const int idx = tid + it * 512;       // 0..1023
      const int r = idx >> 4;
      const int c = (idx & 15) << 2;
      const float4 v = *(const float4*)(g + (size_t)(r0 + r) * 768 + (c0 + c));
      sm.tile[c + 0][r] = f2h_bits(v.x);
      sm.tile[c + 1][r] = f2h_bits(v.y);
      sm.tile[c + 2][r] = f2h_bits(v.z);
      sm.tile[c + 3][r] = f2h_bits(v.w);
    }
    __syncthreads();
#pragma unroll
    for (int it = 0; it < 2; ++it) {
      const int idx = tid + it * 512;
      const int r = idx >> 4;
      const int c = (idx & 15) << 2;
      ushort4 o;
      o.x = sm.tile[r][c + 0]; o.y = sm.tile[r][c + 1];
      o.z = sm.tile[r][c + 2]; o.w = sm.tile[r][c + 3];
      *(ushort4*)(gT + (size_t)(c0 + r) * 4096 + (r0 + c)) = o;
    }
    return;
  }

  // ---- prep block: 64 tokens, x staged in LDS chunks (coalesced) ----
  const int lane = tid & 63;
  const int wv = __builtin_amdgcn_readfirstlane(tid >> 6);  // 0..7 = d-slice
  const int t0 = (bid - 768) * 64;

  float acc[48];
#pragma unroll
  for (int q = 0; q < 48; ++q) acc[q] = 0.f;

  const float* xbase = x + (size_t)t0 * 768;
  auto load_chunk = [&](int c, int b) {
#pragma unroll
    for (int it = 0; it < 3; ++it) {
      const int q = tid + it * 512;         // 0..1535
      const int r = q / 24;
      const int c4 = q % 24;
      const float4 v = *(const float4*)(xbase + (size_t)r * 768 + c * 96 + c4 * 4);
      *(float4*)&sm.x2[b][r][c4 * 4] = v;
    }
  };

  load_chunk(0, 0);
  __syncthreads();
  for (int c = 0; c < 8; ++c) {
    const int cur = c & 1;
    if (c < 7) load_chunk(c + 1, cur ^ 1);
    float xv[12];
#pragma unroll
    for (int rr = 0; rr < 3; ++rr) {
      const f32x4 v = *(const f32x4*)&sm.x2[cur][lane][wv * 12 + rr * 4];
      xv[rr * 4 + 0] = v[0]; xv[rr * 4 + 1] = v[1];
      xv[rr * 4 + 2] = v[2]; xv[rr * 4 + 3] = v[3];
    }
#pragma unroll
    for (int dd = 0; dd < 12; ++dd) {
      const int d = c * 96 + wv * 12 + dd;
      const float xs = xv[dd];
      const float* w1r = W1 + d * 16;
      const float* w2r = W2 + d * 16;
      const float* w3r = W3 + d * 16;
#pragma unroll
      for (int gg = 0; gg < 16; ++gg) {
        acc[gg]      = fmaf(xs, w1r[gg], acc[gg]);
        acc[16 + gg] = fmaf(xs, w2r[gg], acc[16 + gg]);
        acc[32 + gg] = fmaf(xs, w3r[gg], acc[32 + gg]);
      }
    }
    __syncthreads();
  }

  // tree reduce 8 -> 4 -> 2 -> 1
  if (wv >= 4) {
    f32x4* dst = (f32x4*)sm.partial[wv - 4][lane];
#pragma unroll
    for (int q = 0; q < 12; ++q) dst[q] = *(const f32x4*)&acc[q * 4];
  }
  __syncthreads();
  if (wv < 4) {
    const f32x4* src = (const f32x4*)sm.partial[wv][lane];
#pragma unroll
    for (int q = 0; q < 12; ++q) {
      const f32x4 v = src[q];
#pragma unroll
      for (int e = 0; e < 4; ++e) acc[q * 4 + e] += v[e];
    }
  }
  __syncthreads();
  if (wv == 2 || wv == 3) {
    f32x4* dst = (f32x4*)sm.partial[wv - 2][lane];
#pragma unroll
    for (int q = 0; q < 12; ++q) dst[q] = *(const f32x4*)&acc[q * 4];
  }
  __syncthreads();
  if (wv < 2) {
    const f32x4* src = (const f32x4*)sm.partial[wv][lane];
#pragma unroll
    for (int q = 0; q < 12; ++q) {
      const f32x4 v = src[q];
#pragma unroll
      for (int e = 0; e < 4; ++e) acc[q * 4 + e] += v[e];
    }
  }
  __syncthreads();
  if (wv == 1) {
    f32x4* dst = (f32x4*)sm.partial[0][lane];
#pragma unroll
    for (int q = 0; q < 12; ++q) dst[q] = *(const f32x4*)&acc[q * 4];
  }
  __syncthreads();
  if (wv == 0) {
    const f32x4* src = (const f32x4*)sm.partial[0][lane];
#pragma unroll
    for (int q = 0; q < 12; ++q) {
      const f32x4 v = src[q];
#pragma unroll
      for (int e = 0; e < 4; ++e) acc[q * 4 + e] += v[e];
    }
    const float invT = 1.0f / temp[0];
    float* prow = p + (size_t)(t0 + lane) * PSTRIDE;
#pragma unroll
    for (int grp = 0; grp < 3; ++grp) {
      const float* bias = (grp == 0) ? b1 : (grp == 1) ? b2 : b3;
      float z[16];
      float m = -3.0e38f;
#pragma unroll
      for (int q = 0; q < 16; ++q) {
        z[q] = (acc[grp * 16 + q] + bias[q]) * invT;
        m = fmaxf(m, z[q]);
      }
      float s = 0.f;
#pragma unroll
      for (int q = 0; q < 16; ++q) { z[q] = __expf(z[q] - m); s += z[q]; }
      const float rs = 1.0f / s;
#pragma unroll
      for (int q = 0; q < 16; ++q) prow[grp * 16 + q] = z[q] * rs;
    }
  }
}

// ---------------------------------------------------------------------------
// GEMM. BM=128 BN=192 BK=64; 4 waves 2x2, wave tile 64x96,
// v_mfma_f32_32x32x16_f16. A built via v_pk_mul_f16 from per-lane f16 regs.
// Straight-line kt body: 12 ds_reads up front, stage next, 4 setprio MFMA
// clusters. Raw barriers, vmcnt(0) only at kt end. XCD swizzle.
// ---------------------------------------------------------------------------
__global__ __launch_bounds__(256, 2) void k_gemm(const float* __restrict__ p_g,
                                                 const ushort_t* __restrict__ gT,
                                                 float* __restrict__ out) {
  __shared__ ushort_t Bt[2][192 * 64];        // 49,152 B
  __shared__ float p1T[16 * 128];             //  8,192 B

  const int tid = threadIdx.x;
  const int lane = tid & 63;
  const int wv = __builtin_amdgcn_readfirstlane(tid >> 6);
  const int wm = wv >> 1, wn = wv & 1;
  const int g = lane >> 5;                    // k-half 0/1
  const int l31 = lane & 31;

  // XCD-aware swizzle over 512 blocks (512 % 8 == 0 -> bijective)
  const int f = blockIdx.y * 128 + blockIdx.x;
  const int w = (f & 7) * 64 + (f >> 3);
  const int m0 = (w & 127) * 128;
  const int n0 = (w >> 7) * 192;

  // p1T[i][row] cooperative build (f32)
  if (tid < 128) {
    const float* pr = p_g + (size_t)(m0 + tid) * PSTRIDE;
#pragma unroll
    for (int qq = 0; qq < 4; ++qq) {
      const f32x4 v = *(const f32x4*)(pr + qq * 4);
#pragma unroll
      for (int e = 0; e < 4; ++e) p1T[(qq * 4 + e) * 128 + tid] = v[e];
    }
  }

  // per-lane p2 (16 f16-broadcast pairs) and p3 (own k-half, 8 f32) per m-rep
  const int rowA0 = m0 + wm * 64 + l31;
  half2v p2h[2][16];
  float p3r[2][8];
#pragma unroll
  for (int mr = 0; mr < 2; ++mr) {
    const float* pr = p_g + (size_t)(rowA0 + mr * 32) * PSTRIDE;
#pragma unroll
    for (int qq = 0; qq < 4; ++qq) {
      const f32x4 v = *(const f32x4*)(pr + 16 + qq * 4);
#pragma unroll
      for (int e = 0; e < 4; ++e)
        p2h[mr][qq * 4 + e] = cvt_pkrtz2(v[e], v[e]);
    }
#pragma unroll
    for (int qq = 0; qq < 2; ++qq) {
      const f32x4 v = *(const f32x4*)(pr + 32 + 8 * g + qq * 4);
      p3r[mr][qq * 4 + 0] = v[0]; p3r[mr][qq * 4 + 1] = v[1];
      p3r[mr][qq * 4 + 2] = v[2]; p3r[mr][qq * 4 + 3] = v[3];
    }
  }

  // B staging: linear LDS dest + inverse-swizzled source (16B chunks)
  const int srow = wv * 48 + (lane >> 3);
  const int schunk = (lane & 7) ^ (lane >> 3);
  const ushort_t* sbase = gT + (size_t)(n0 + srow) * 4096 + schunk * 8;
  auto stage = [&](int buf, int kt) {
    const ushort_t* src = sbase + kt * 64;
#pragma unroll
    for (int q = 0; q < 6; ++q) {
      __builtin_amdgcn_global_load_lds((gptr_t)(src + (size_t)q * 8 * 4096),
                                       (lptr_t)&Bt[buf][(wv * 48 + q * 8) * 64], 16, 0, 0);
    }
  };

  f32x16 acc[2][3];
#pragma unroll
  for (int mr = 0; mr < 2; ++mr)
#pragma unroll
    for (int nf = 0; nf < 3; ++nf)
#pragma unroll
      for (int e = 0; e < 16; ++e) acc[mr][nf][e] = 0.f;

  stage(0, 0);
  asm volatile("s_waitcnt vmcnt(0) lgkmcnt(0)" ::: "memory");
  __builtin_amdgcn_s_barrier();

  const int rowLoc0 = wm * 64 + l31;
  for (int io = 0; io < 16; ++io) {           // i-index (p1)
    // p1p3 in f16 pairs, rebuilt once per io
    half2v p1p3h[2][4];
#pragma unroll
    for (int mr = 0; mr < 2; ++mr) {
      const float p1v = p1T[io * 128 + rowLoc0 + mr * 32];
#pragma unroll
      for (int q = 0; q < 4; ++q)
        p1p3h[mr][q] = cvt_pkrtz2(p1v * p3r[mr][2 * q],
                                  p1v * p3r[mr][2 * q + 1]);
    }
#pragma unroll
    for (int kq = 0; kq < 4; ++kq) {
      const int kt = io * 4 + kq;
      const ushort_t* bbuf = Bt[kq & 1];

      // issue all 12 B-fragment reads up front (counted lgkm waits)
      half8 b[4][3];
#pragma unroll
      for (int s = 0; s < 4; ++s) {
        const int cd = 2 * s + g;
#pragma unroll
        for (int nf = 0; nf < 3; ++nf) {
          const int r = wn * 96 + nf * 32 + l31;
          b[s][nf] = *(const half8*)&bbuf[r * 64 + ((cd ^ (r & 7)) << 3)];
        }
      }
      // prefetch next K64 tile
      if (kq < 3 || io < 15) stage((kq + 1) & 1, kt + 1);

#pragma unroll
      for (int s = 0; s < 4; ++s) {
        const int j = kq * 4 + s;             // static p2 index
        half8 a[2];
#pragma unroll
        for (int mr = 0; mr < 2; ++mr) {
          union { half2v h2[4]; half8 h8; } pk;
#pragma unroll
          for (int q = 0; q < 4; ++q) pk.h2[q] = p2h[mr][j] * p1p3h[mr][q];
          a[mr] = pk.h8;
        }
        __builtin_amdgcn_s_setprio(1);
#pragma unroll
        for (int mr = 0; mr < 2; ++mr)
#pragma unroll
          for (int nf = 0; nf < 3; ++nf)
            acc[mr][nf] = __builtin_amdgcn_mfma_f32_32x32x16_f16(a[mr], b[s][nf], acc[mr][nf], 0, 0, 0);
        __builtin_amdgcn_s_setprio(0);
      }
      asm volatile("s_waitcnt vmcnt(0)" ::: "memory");
      __builtin_amdgcn_s_barrier();
    }
  }

  // epilogue: 32x32 C/D: col = lane&31, row = (reg&3)+8*(reg>>2)+4*(lane>>5)
#pragma unroll
  for (int mr = 0; mr < 2; ++mr)
#pragma unroll
    for (int nf = 0; nf < 3; ++nf)
#pragma unroll
      for (int reg = 0; reg < 16; ++reg) {
        const int row = (reg & 3) + 8 * (reg >> 2) + 4 * g;
        const int t = m0 + wm * 64 + mr * 32 + row;
        out[(size_t)t * 768 + n0 + wn * 96 + nf * 32 + l31] = acc[mr][nf][reg];
      }
}

// ---------------------------------------------------------------------------
extern "C" void kernel_launch(void* const* d_in, const int* in_sizes, int n_in,
                              void* d_out, int out_size, void* d_ws, size_t ws_size,
                              hipStream_t stream) {
  (void)in_sizes; (void)n_in; (void)out_size; (void)ws_size;
  const float* x    = (const float*)d_in[0];
  const float* W1   = (const float*)d_in[1];
  const float* b1   = (const float*)d_in[2];
  const float* W2   = (const float*)d_in[3];
  const float* b2   = (const float*)d_in[4];
  const float* W3   = (const float*)d_in[5];
  const float* b3   = (const float*)d_in[6];
  const float* grid = (const float*)d_in[7];
  const float* temp = (const float*)d_in[8];
  float* out = (float*)d_out;

  // ws: gT f16 [768][4096] = 6,291,456 B ; p f32 [16384][52] = 3,407,872 B
  ushort_t* gT = (ushort_t*)d_ws;
  float* p = (float*)((char*)d_ws + 6291456);

  k_pre<<<dim3(1024), 512, 0, stream>>>(grid, gT, x, W1, b1, W2, b2, W3, b3, temp, p);
  k_gemm<<<dim3(128, 4), 256, 0, stream>>>(p, gT, out);
}